// Round 1
// baseline (1284.826 us; speedup 1.0000x reference)
//
#include <hip/hip_runtime.h>

#define F 128
#define BN 64

// ---------------- CSR build ----------------

__global__ __launch_bounds__(256) void count_kernel(const int* __restrict__ dst,
                                                    int* __restrict__ cnt, int e) {
    int i = blockIdx.x * 256 + threadIdx.x;
    if (i < e) atomicAdd(&cnt[dst[i]], 1);
}

__global__ __launch_bounds__(256) void dinv_kernel(const int* __restrict__ cnt,
                                                   float* __restrict__ dinv, int n) {
    int i = blockIdx.x * 256 + threadIdx.x;
    if (i < n) dinv[i] = rsqrtf((float)(cnt[i] + 1));  // +1 self loop
}

__global__ __launch_bounds__(1024) void scan_kernel(const int* __restrict__ cnt,
                                                    int* __restrict__ offs, int n) {
    __shared__ int sm[1024];
    int tid = threadIdx.x;
    int chunk = (n + 1023) >> 10;
    int b = tid * chunk;
    int e = b + chunk; if (e > n) e = n;
    int s = 0;
    for (int i = b; i < e; i++) s += cnt[i];
    sm[tid] = s;
    __syncthreads();
    for (int d = 1; d < 1024; d <<= 1) {
        int v = 0;
        if (tid >= d) v = sm[tid - d];
        __syncthreads();
        if (tid >= d) sm[tid] += v;
        __syncthreads();
    }
    int run = (tid == 0) ? 0 : sm[tid - 1];
    for (int i = b; i < e; i++) { offs[i] = run; run += cnt[i]; }
    if (tid == 1023) offs[n] = sm[1023];
}

__global__ __launch_bounds__(256) void fill_kernel(const int* __restrict__ src,
                                                   const int* __restrict__ dst,
                                                   const int* __restrict__ offs,
                                                   int* __restrict__ cursor,
                                                   const float* __restrict__ dinv,
                                                   int2* __restrict__ csr, int e) {
    int i = blockIdx.x * 256 + threadIdx.x;
    if (i >= e) return;
    int s = src[i], d = dst[i];
    int pos = atomicAdd(&cursor[d], 1);
    int2 pk;
    pk.x = s;
    pk.y = __float_as_int(dinv[s] * dinv[d]);
    csr[offs[d] + pos] = pk;
}

// ---------------- GEMM: out[n][128] = h[n][128] @ W[128][128] ----------------
// grid.y in {0,1} selects 64-feature half. LDS: Ws 32KB + Hs 32KB = 64KB.

__global__ __launch_bounds__(256) void gemm_kernel(const float* __restrict__ h,
                                                   const float* __restrict__ W,
                                                   float* __restrict__ out, int n) {
    __shared__ float Ws[128 * 64];   // Ws[k][fh]
    __shared__ float Hs[BN * 128];   // Hs[nn][k ^ ((nn&7)<<2)]  (bank swizzle)
    const int tid = threadIdx.x;
    const int half = blockIdx.y;

    // stage W half once per block (coalesced 256B/wave)
    for (int i = tid; i < 128 * 64; i += 256) {
        int k = i >> 6, fh = i & 63;
        Ws[i] = W[k * F + (half << 6) + fh];
    }

    const int fg = tid & 15;         // 16 feature groups * 4 feats = 64
    const int ng = tid >> 4;         // 16 node groups * 4 nodes = 64
    const int f0 = fg << 2;
    const int n0 = ng << 2;
    const int nchunk = (n + BN - 1) / BN;

    for (int c = blockIdx.x; c < nchunk; c += gridDim.x) {
        const int base = c * BN;
        __syncthreads();             // protect Hs from previous chunk's readers
        for (int i = tid; i < BN * 128; i += 256) {
            int nn = i >> 7, k = i & 127;
            int node = base + nn;
            float v = (node < n) ? h[(size_t)node * F + k] : 0.0f;
            Hs[(nn << 7) + (k ^ ((nn & 7) << 2))] = v;
        }
        __syncthreads();

        float acc[4][4];
        #pragma unroll
        for (int a = 0; a < 4; a++)
            #pragma unroll
            for (int b = 0; b < 4; b++) acc[a][b] = 0.0f;

        #pragma unroll 2
        for (int kk = 0; kk < 128; kk += 4) {
            float4 w0 = *(const float4*)&Ws[((kk + 0) << 6) + f0];
            float4 w1 = *(const float4*)&Ws[((kk + 1) << 6) + f0];
            float4 w2 = *(const float4*)&Ws[((kk + 2) << 6) + f0];
            float4 w3 = *(const float4*)&Ws[((kk + 3) << 6) + f0];
            #pragma unroll
            for (int j = 0; j < 4; j++) {
                const int nn = n0 + j;
                float4 hv = *(const float4*)&Hs[(nn << 7) + (kk ^ ((nn & 7) << 2))];
                acc[j][0] += hv.x * w0.x + hv.y * w1.x + hv.z * w2.x + hv.w * w3.x;
                acc[j][1] += hv.x * w0.y + hv.y * w1.y + hv.z * w2.y + hv.w * w3.y;
                acc[j][2] += hv.x * w0.z + hv.y * w1.z + hv.z * w2.z + hv.w * w3.z;
                acc[j][3] += hv.x * w0.w + hv.y * w1.w + hv.z * w2.w + hv.w * w3.w;
            }
        }

        #pragma unroll
        for (int j = 0; j < 4; j++) {
            int node = base + n0 + j;
            if (node < n) {
                float4 v = make_float4(acc[j][0], acc[j][1], acc[j][2], acc[j][3]);
                *(float4*)&out[(size_t)node * F + (half << 6) + f0] = v;
            }
        }
    }
}

// ---------------- Aggregate: out[i] = relu(sum_{e: dst=i} norm*hl[src] + dinv_i^2*hl[i] + b) ----

template <int POOL>
__global__ __launch_bounds__(128) void agg_kernel(const float* __restrict__ hl,
                                                  const int* __restrict__ offs,
                                                  const int2* __restrict__ csr,
                                                  const float* __restrict__ dinv,
                                                  const float* __restrict__ bias,
                                                  float* __restrict__ out,
                                                  const int* __restrict__ batch, int n) {
    int i = blockIdx.x;
    if (i >= n) return;
    int f = threadIdx.x;
    float di = dinv[i];
    float acc = hl[(size_t)i * F + f] * di * di;   // self loop
    int e0 = offs[i], e1 = offs[i + 1];
    for (int e = e0; e < e1; e++) {
        int2 pk = csr[e];                          // broadcast 8B load
        acc += hl[(size_t)pk.x * F + f] * __int_as_float(pk.y);
    }
    float r = fmaxf(acc + bias[f], 0.0f);
    if (POOL) {
        atomicMax((int*)&out[(size_t)batch[i] * F + f], __float_as_int(r));  // r >= 0
    } else {
        out[(size_t)i * F + f] = r;
    }
}

// ---------------- MLP head + log_softmax ----------------

__global__ __launch_bounds__(128) void mlp_kernel(const float* __restrict__ pooled,
                                                  const float* __restrict__ Wp1,
                                                  const float* __restrict__ bp1,
                                                  const float* __restrict__ Wp2,
                                                  const float* __restrict__ bp2,
                                                  float* __restrict__ out) {
    __shared__ float pl[F];
    __shared__ float s0[2], s1[2];
    int g = blockIdx.x, t = threadIdx.x;
    pl[t] = pooled[(size_t)g * F + t];
    __syncthreads();
    float a = bp1[t];
    #pragma unroll 8
    for (int k = 0; k < F; k++) a += pl[k] * Wp1[k * F + t];
    float p0 = a * Wp2[t * 2 + 0];
    float p1 = a * Wp2[t * 2 + 1];
    #pragma unroll
    for (int d = 32; d > 0; d >>= 1) {
        p0 += __shfl_down(p0, d, 64);
        p1 += __shfl_down(p1, d, 64);
    }
    if ((t & 63) == 0) { s0[t >> 6] = p0; s1[t >> 6] = p1; }
    __syncthreads();
    if (t == 0) {
        float l0 = s0[0] + s0[1] + bp2[0];
        float l1 = s1[0] + s1[1] + bp2[1];
        float m = fmaxf(l0, l1);
        float lse = m + logf(expf(l0 - m) + expf(l1 - m));
        out[g * 2 + 0] = l0 - lse;
        out[g * 2 + 1] = l1 - lse;
    }
}

// ---------------- launch ----------------

extern "C" void kernel_launch(void* const* d_in, const int* in_sizes, int n_in,
                              void* d_out, int out_size, void* d_ws, size_t ws_size,
                              hipStream_t stream) {
    const float* x    = (const float*)d_in[0];
    const int*   ei   = (const int*)d_in[1];
    const int*   batch= (const int*)d_in[2];
    const float* W1 = (const float*)d_in[3];  const float* b1 = (const float*)d_in[4];
    const float* W2 = (const float*)d_in[5];  const float* b2 = (const float*)d_in[6];
    const float* W3 = (const float*)d_in[7];  const float* b3 = (const float*)d_in[8];
    const float* Wp1= (const float*)d_in[9];  const float* bp1= (const float*)d_in[10];
    const float* Wp2= (const float*)d_in[11]; const float* bp2= (const float*)d_in[12];

    const int N = in_sizes[0] / F;
    const int E = in_sizes[1] / 2;
    const int G = out_size / 2;

    char* w = (char*)d_ws;
    size_t off = 0;
    auto alloc = [&](size_t bytes) -> void* {
        void* p = w + off;
        off = (off + bytes + 255) & ~(size_t)255;
        return p;
    };
    float* bufA   = (float*)alloc((size_t)N * F * 4);
    float* bufB   = (float*)alloc((size_t)N * F * 4);
    int*   deg    = (int*)alloc((size_t)N * 4);
    int*   cursor = (int*)alloc((size_t)N * 4);
    int*   offs   = (int*)alloc((size_t)(N + 1) * 4);
    float* dinv   = (float*)alloc((size_t)N * 4);
    int2*  csr    = (int2*)alloc((size_t)E * 8);
    float* pooled = (float*)alloc((size_t)G * F * 4);

    const int* srcp = ei;
    const int* dstp = ei + E;

    hipMemsetAsync(deg,    0, (size_t)N * 4, stream);
    hipMemsetAsync(cursor, 0, (size_t)N * 4, stream);
    hipMemsetAsync(pooled, 0, (size_t)G * F * 4, stream);

    const int eb = (E + 255) / 256;
    const int nb = (N + 255) / 256;
    count_kernel<<<eb, 256, 0, stream>>>(dstp, deg, E);
    dinv_kernel<<<nb, 256, 0, stream>>>(deg, dinv, N);
    scan_kernel<<<1, 1024, 0, stream>>>(deg, offs, N);
    fill_kernel<<<eb, 256, 0, stream>>>(srcp, dstp, offs, cursor, dinv, csr, E);

    dim3 gg(512, 2);
    gemm_kernel<<<gg, 256, 0, stream>>>(x, W1, bufA, N);
    agg_kernel<0><<<N, 128, 0, stream>>>(bufA, offs, csr, dinv, b1, bufB, nullptr, N);
    gemm_kernel<<<gg, 256, 0, stream>>>(bufB, W2, bufA, N);
    agg_kernel<0><<<N, 128, 0, stream>>>(bufA, offs, csr, dinv, b2, bufB, nullptr, N);
    gemm_kernel<<<gg, 256, 0, stream>>>(bufB, W3, bufA, N);
    agg_kernel<1><<<N, 128, 0, stream>>>(bufA, offs, csr, dinv, b3, pooled, batch, N);
    mlp_kernel<<<G, 128, 0, stream>>>(pooled, Wp1, bp1, Wp2, bp2, (float*)d_out);
}

// Round 2
// 1211.908 us; speedup vs baseline: 1.0602x; 1.0602x over previous
//
#include <hip/hip_runtime.h>

#define F 128
#define BN 64

// ---------------- CSR build ----------------

__global__ __launch_bounds__(256) void count_kernel(const int* __restrict__ dst,
                                                    int* __restrict__ cnt, int e) {
    int i = blockIdx.x * 256 + threadIdx.x;
    if (i < e) atomicAdd(&cnt[dst[i]], 1);
}

__global__ __launch_bounds__(256) void dinv_kernel(const int* __restrict__ cnt,
                                                   float* __restrict__ dinv, int n) {
    int i = blockIdx.x * 256 + threadIdx.x;
    if (i < n) dinv[i] = rsqrtf((float)(cnt[i] + 1));  // +1 self loop
}

__global__ __launch_bounds__(1024) void scan_kernel(const int* __restrict__ cnt,
                                                    int* __restrict__ offs, int n) {
    __shared__ int sm[1024];
    int tid = threadIdx.x;
    int chunk = (n + 1023) >> 10;
    int b = tid * chunk;
    int e = b + chunk; if (e > n) e = n;
    int s = 0;
    for (int i = b; i < e; i++) s += cnt[i];
    sm[tid] = s;
    __syncthreads();
    for (int d = 1; d < 1024; d <<= 1) {
        int v = 0;
        if (tid >= d) v = sm[tid - d];
        __syncthreads();
        if (tid >= d) sm[tid] += v;
        __syncthreads();
    }
    int run = (tid == 0) ? 0 : sm[tid - 1];
    for (int i = b; i < e; i++) { offs[i] = run; run += cnt[i]; }
    if (tid == 1023) offs[n] = sm[1023];
}

__global__ __launch_bounds__(256) void fill_kernel(const int* __restrict__ src,
                                                   const int* __restrict__ dst,
                                                   const int* __restrict__ offs,
                                                   int* __restrict__ cursor,
                                                   const float* __restrict__ dinv,
                                                   int2* __restrict__ csr, int e) {
    int i = blockIdx.x * 256 + threadIdx.x;
    if (i >= e) return;
    int s = src[i], d = dst[i];
    int pos = atomicAdd(&cursor[d], 1);
    int2 pk;
    pk.x = s;
    pk.y = __float_as_int(dinv[s] * dinv[d]);
    csr[offs[d] + pos] = pk;
}

// ---------------- GEMM: out[n][128] = h[n][128] @ W[128][128] ----------------

__global__ __launch_bounds__(256) void gemm_kernel(const float* __restrict__ h,
                                                   const float* __restrict__ W,
                                                   float* __restrict__ out, int n) {
    __shared__ float Ws[128 * 64];   // Ws[k][fh]
    __shared__ float Hs[BN * 128];   // Hs[nn][k ^ ((nn&7)<<2)]  (bank swizzle)
    const int tid = threadIdx.x;
    const int half = blockIdx.y;

    for (int i = tid; i < 128 * 64; i += 256) {
        int k = i >> 6, fh = i & 63;
        Ws[i] = W[k * F + (half << 6) + fh];
    }

    const int fg = tid & 15;
    const int ng = tid >> 4;
    const int f0 = fg << 2;
    const int n0 = ng << 2;
    const int nchunk = (n + BN - 1) / BN;

    for (int c = blockIdx.x; c < nchunk; c += gridDim.x) {
        const int base = c * BN;
        __syncthreads();
        for (int i = tid; i < BN * 128; i += 256) {
            int nn = i >> 7, k = i & 127;
            int node = base + nn;
            float v = (node < n) ? h[(size_t)node * F + k] : 0.0f;
            Hs[(nn << 7) + (k ^ ((nn & 7) << 2))] = v;
        }
        __syncthreads();

        float acc[4][4];
        #pragma unroll
        for (int a = 0; a < 4; a++)
            #pragma unroll
            for (int b = 0; b < 4; b++) acc[a][b] = 0.0f;

        #pragma unroll 2
        for (int kk = 0; kk < 128; kk += 4) {
            float4 w0 = *(const float4*)&Ws[((kk + 0) << 6) + f0];
            float4 w1 = *(const float4*)&Ws[((kk + 1) << 6) + f0];
            float4 w2 = *(const float4*)&Ws[((kk + 2) << 6) + f0];
            float4 w3 = *(const float4*)&Ws[((kk + 3) << 6) + f0];
            #pragma unroll
            for (int j = 0; j < 4; j++) {
                const int nn = n0 + j;
                float4 hv = *(const float4*)&Hs[(nn << 7) + (kk ^ ((nn & 7) << 2))];
                acc[j][0] += hv.x * w0.x + hv.y * w1.x + hv.z * w2.x + hv.w * w3.x;
                acc[j][1] += hv.x * w0.y + hv.y * w1.y + hv.z * w2.y + hv.w * w3.y;
                acc[j][2] += hv.x * w0.z + hv.y * w1.z + hv.z * w2.z + hv.w * w3.z;
                acc[j][3] += hv.x * w0.w + hv.y * w1.w + hv.z * w2.w + hv.w * w3.w;
            }
        }

        #pragma unroll
        for (int j = 0; j < 4; j++) {
            int node = base + n0 + j;
            if (node < n) {
                float4 v = make_float4(acc[j][0], acc[j][1], acc[j][2], acc[j][3]);
                *(float4*)&out[(size_t)node * F + (half << 6) + f0] = v;
            }
        }
    }
}

// ---------------- Aggregate: wave-per-node, float2 per lane, edge loop unrolled 4x ----

template <int POOL>
__global__ __launch_bounds__(256) void agg_kernel(const float* __restrict__ hl,
                                                  const int* __restrict__ offs,
                                                  const int2* __restrict__ csr,
                                                  const float* __restrict__ dinv,
                                                  const float* __restrict__ bias,
                                                  float* __restrict__ out,
                                                  const int* __restrict__ batch, int n) {
    const int lane = threadIdx.x & 63;
    const int wid  = blockIdx.x * 4 + (threadIdx.x >> 6);   // wave id == node id
    if (wid >= n) return;
    const int i = wid;
    const float2* __restrict__ hl2 = (const float2*)hl;

    float di = dinv[i];
    float2 self = hl2[(size_t)i * 64 + lane];
    float ax = self.x * di * di;
    float ay = self.y * di * di;

    int e0 = offs[i], e1 = offs[i + 1];
    int e = e0;
    for (; e + 4 <= e1; e += 4) {
        int2 p0 = csr[e + 0];
        int2 p1 = csr[e + 1];
        int2 p2 = csr[e + 2];
        int2 p3 = csr[e + 3];
        float2 r0 = hl2[(size_t)p0.x * 64 + lane];
        float2 r1 = hl2[(size_t)p1.x * 64 + lane];
        float2 r2 = hl2[(size_t)p2.x * 64 + lane];
        float2 r3 = hl2[(size_t)p3.x * 64 + lane];
        float n0f = __int_as_float(p0.y), n1f = __int_as_float(p1.y);
        float n2f = __int_as_float(p2.y), n3f = __int_as_float(p3.y);
        ax += r0.x * n0f + r1.x * n1f + r2.x * n2f + r3.x * n3f;
        ay += r0.y * n0f + r1.y * n1f + r2.y * n2f + r3.y * n3f;
    }
    for (; e < e1; e++) {
        int2 pk = csr[e];
        float2 r = hl2[(size_t)pk.x * 64 + lane];
        float nf = __int_as_float(pk.y);
        ax += r.x * nf;
        ay += r.y * nf;
    }

    float2 bv = ((const float2*)bias)[lane];
    float rx = fmaxf(ax + bv.x, 0.0f);
    float ry = fmaxf(ay + bv.y, 0.0f);

    if (POOL) {
        int g = batch[i];
        atomicMax((int*)&out[(size_t)g * F + 2 * lane + 0], __float_as_int(rx));
        atomicMax((int*)&out[(size_t)g * F + 2 * lane + 1], __float_as_int(ry));
    } else {
        ((float2*)out)[(size_t)i * 64 + lane] = make_float2(rx, ry);
    }
}

// ---------------- MLP head + log_softmax ----------------

__global__ __launch_bounds__(128) void mlp_kernel(const float* __restrict__ pooled,
                                                  const float* __restrict__ Wp1,
                                                  const float* __restrict__ bp1,
                                                  const float* __restrict__ Wp2,
                                                  const float* __restrict__ bp2,
                                                  float* __restrict__ out) {
    __shared__ float pl[F];
    __shared__ float s0[2], s1[2];
    int g = blockIdx.x, t = threadIdx.x;
    pl[t] = pooled[(size_t)g * F + t];
    __syncthreads();
    float a = bp1[t];
    #pragma unroll 8
    for (int k = 0; k < F; k++) a += pl[k] * Wp1[k * F + t];
    float p0 = a * Wp2[t * 2 + 0];
    float p1 = a * Wp2[t * 2 + 1];
    #pragma unroll
    for (int d = 32; d > 0; d >>= 1) {
        p0 += __shfl_down(p0, d, 64);
        p1 += __shfl_down(p1, d, 64);
    }
    if ((t & 63) == 0) { s0[t >> 6] = p0; s1[t >> 6] = p1; }
    __syncthreads();
    if (t == 0) {
        float l0 = s0[0] + s0[1] + bp2[0];
        float l1 = s1[0] + s1[1] + bp2[1];
        float m = fmaxf(l0, l1);
        float lse = m + logf(expf(l0 - m) + expf(l1 - m));
        out[g * 2 + 0] = l0 - lse;
        out[g * 2 + 1] = l1 - lse;
    }
}

// ---------------- launch ----------------

extern "C" void kernel_launch(void* const* d_in, const int* in_sizes, int n_in,
                              void* d_out, int out_size, void* d_ws, size_t ws_size,
                              hipStream_t stream) {
    const float* x    = (const float*)d_in[0];
    const int*   ei   = (const int*)d_in[1];
    const int*   batch= (const int*)d_in[2];
    const float* W1 = (const float*)d_in[3];  const float* b1 = (const float*)d_in[4];
    const float* W2 = (const float*)d_in[5];  const float* b2 = (const float*)d_in[6];
    const float* W3 = (const float*)d_in[7];  const float* b3 = (const float*)d_in[8];
    const float* Wp1= (const float*)d_in[9];  const float* bp1= (const float*)d_in[10];
    const float* Wp2= (const float*)d_in[11]; const float* bp2= (const float*)d_in[12];

    const int N = in_sizes[0] / F;
    const int E = in_sizes[1] / 2;
    const int G = out_size / 2;

    char* w = (char*)d_ws;
    size_t off = 0;
    auto alloc = [&](size_t bytes) -> void* {
        void* p = w + off;
        off = (off + bytes + 255) & ~(size_t)255;
        return p;
    };
    float* bufA   = (float*)alloc((size_t)N * F * 4);
    float* bufB   = (float*)alloc((size_t)N * F * 4);
    int*   deg    = (int*)alloc((size_t)N * 4);
    int*   cursor = (int*)alloc((size_t)N * 4);
    int*   offs   = (int*)alloc((size_t)(N + 1) * 4);
    float* dinv   = (float*)alloc((size_t)N * 4);
    int2*  csr    = (int2*)alloc((size_t)E * 8);
    float* pooled = (float*)alloc((size_t)G * F * 4);

    const int* srcp = ei;
    const int* dstp = ei + E;

    hipMemsetAsync(deg,    0, (size_t)N * 4, stream);
    hipMemsetAsync(cursor, 0, (size_t)N * 4, stream);
    hipMemsetAsync(pooled, 0, (size_t)G * F * 4, stream);

    const int eb = (E + 255) / 256;
    const int nb = (N + 255) / 256;
    count_kernel<<<eb, 256, 0, stream>>>(dstp, deg, E);
    dinv_kernel<<<nb, 256, 0, stream>>>(deg, dinv, N);
    scan_kernel<<<1, 1024, 0, stream>>>(deg, offs, N);
    fill_kernel<<<eb, 256, 0, stream>>>(srcp, dstp, offs, cursor, dinv, csr, E);

    const int ab = (N + 3) / 4;   // 4 waves (nodes) per block
    dim3 gg(512, 2);
    gemm_kernel<<<gg, 256, 0, stream>>>(x, W1, bufA, N);
    agg_kernel<0><<<ab, 256, 0, stream>>>(bufA, offs, csr, dinv, b1, bufB, nullptr, N);
    gemm_kernel<<<gg, 256, 0, stream>>>(bufB, W2, bufA, N);
    agg_kernel<0><<<ab, 256, 0, stream>>>(bufA, offs, csr, dinv, b2, bufB, nullptr, N);
    gemm_kernel<<<gg, 256, 0, stream>>>(bufB, W3, bufA, N);
    agg_kernel<1><<<ab, 256, 0, stream>>>(bufA, offs, csr, dinv, b3, pooled, batch, N);
    mlp_kernel<<<G, 128, 0, stream>>>(pooled, Wp1, bp1, Wp2, bp2, (float*)d_out);
}